// Round 7
// baseline (222.280 us; speedup 1.0000x reference)
//
#include <hip/hip_runtime.h>

// F0=64, F1=128, F2=64. n<=65536, buckets of 128 nodes, slotted CSR, CAP/bucket.
// Deterministic binning (no global atomics), NBLK=1024 blocks for latency hiding:
//   hist_edges(1024+1) -> scan_hist(2*nb, 1024 partials) -> scatter_binned(1024)
// prep_a: src-deg -> norm_src; dst 256-bin counting sort keyed (local, src-half)
//         -> node_rng4 (start, mid, end) + srt + norm_dst.
// xcast:  xb = bf16(h * norm_src), wide streaming kernel.
// Gather stages are SRC-SPLIT two-phase so each half-table (3.2 MB) is
// L2-resident per XCD: phase0 (lo src) raw f32 partials via nontemporal,
// phase1 (hi src) adds + norm (+bias) + final store.
// gemm12: MFMA fused both layers per 64-node tile (W images pre-built).

#define NBMAX 512
#define CAPLOG 12
#define CAP (1 << CAPLOG)
#define NBLK 1024

typedef __attribute__((ext_vector_type(8))) short bf16x8;
typedef __attribute__((ext_vector_type(4))) float f32x4;

__device__ inline unsigned short f2bf(float f) {
    unsigned int u = __float_as_uint(f);
    unsigned int r = (u + 0x7FFFu + ((u >> 16) & 1u)) >> 16;  // RNE
    return (unsigned short)r;
}
__device__ inline float bf2f_lo(unsigned int u) { return __uint_as_float(u << 16); }
__device__ inline float bf2f_hi(unsigned int u) { return __uint_as_float(u & 0xFFFF0000u); }

// K1: streaming edge pass -> per-block private hist rows.
// hist[(side*NBLK + blk)*NBMAX + bucket]. LAST block pre-converts W1/W2.
__global__ __launch_bounds__(256) void hist_edges(const int* __restrict__ src,
        const int* __restrict__ dst, int* __restrict__ hist, int n_edges, int nb,
        const float* __restrict__ W1, const float* __restrict__ W2,
        unsigned short* __restrict__ w1t_g, unsigned short* __restrict__ w2t_g) {
    if (blockIdx.x == NBLK) {
        for (int i = threadIdx.x; i < 8192; i += 256) {   // W1[64][128] -> [n][k] pad 72
            int k = i >> 7, nn = i & 127;
            w1t_g[nn * 72 + k] = f2bf(W1[i]);
        }
        for (int i = threadIdx.x; i < 8192; i += 256) {   // W2[128][64] -> [n][k] pad 136
            int k = i >> 6, nn = i & 63;
            w2t_g[nn * 136 + k] = f2bf(W2[i]);
        }
        return;
    }
    __shared__ int hs[NBMAX], hd[NBMAX];
    for (int i = threadIdx.x; i < nb; i += 256) { hs[i] = 0; hd[i] = 0; }
    __syncthreads();
    int chunk = (n_edges + NBLK - 1) / NBLK;
    int e0 = blockIdx.x * chunk;
    int e1 = e0 + chunk; if (e1 > n_edges) e1 = n_edges;
    for (int e = e0 + (int)threadIdx.x; e < e1; e += 256) {
        atomicAdd(&hs[src[e] >> 7], 1);
        atomicAdd(&hd[dst[e] >> 7], 1);
    }
    __syncthreads();
    int* rs = hist + (size_t)blockIdx.x * NBMAX;
    int* rd = hist + (size_t)(NBLK + blockIdx.x) * NBMAX;
    for (int i = threadIdx.x; i < nb; i += 256) { rs[i] = hs[i]; rd[i] = hd[i]; }
}

// K2: block j scans NBLK per-block counts of one (side,bucket); thread t owns
// blocks 4t..4t+3 (serial), 256-thread scan across thread sums.
__global__ __launch_bounds__(256) void scan_hist(const int* __restrict__ hist,
        int* __restrict__ offs, int* __restrict__ cnt_s, int* __restrict__ cnt_d,
        int nb) {
    __shared__ int wtot[4];
    int j = blockIdx.x;
    int side = j >= nb ? 1 : 0;
    int bucket = j - side * nb;
    const int tid = threadIdx.x;
    size_t b0 = (size_t)(side * NBLK + tid * 4) * NBMAX + bucket;
    int v0 = hist[b0];
    int v1 = hist[b0 + NBMAX];
    int v2 = hist[b0 + 2 * NBMAX];
    int v3 = hist[b0 + 3 * NBMAX];
    int s = v0 + v1 + v2 + v3;
    int lane = tid & 63, wid = tid >> 6;
    int incl = s;
    #pragma unroll
    for (int d = 1; d < 64; d <<= 1) {
        int t = __shfl_up(incl, d, 64);
        if (lane >= d) incl += t;
    }
    if (lane == 63) wtot[wid] = incl;
    __syncthreads();
    int pre = 0;
    #pragma unroll
    for (int k = 0; k < 3; ++k) if (k < wid) pre += wtot[k];
    int eb = pre + incl - s;
    offs[b0]             = eb;
    offs[b0 + NBMAX]     = eb + v0;
    offs[b0 + 2 * NBMAX] = eb + v0 + v1;
    offs[b0 + 3 * NBMAX] = eb + v0 + v1 + v2;
    if (tid == 255) {
        int tot = eb + s;
        if (side) cnt_d[bucket] = tot; else cnt_s[bucket] = tot;
    }
}

// K3: re-read edges, LDS cursors seeded from offs, scatter. LDS atomics only.
// src entry: 1B local id. dst entry: (dst&127)<<25 | src.
__global__ __launch_bounds__(256) void scatter_binned(const int* __restrict__ src,
        const int* __restrict__ dst, const int* __restrict__ offs,
        unsigned char* __restrict__ ss, unsigned int* __restrict__ sd,
        int n_edges, int nb) {
    __shared__ int cs[NBMAX], cd[NBMAX];
    for (int i = threadIdx.x; i < nb; i += 256) {
        cs[i] = offs[(size_t)blockIdx.x * NBMAX + i];
        cd[i] = offs[(size_t)(NBLK + blockIdx.x) * NBMAX + i];
    }
    __syncthreads();
    int chunk = (n_edges + NBLK - 1) / NBLK;
    int e0 = blockIdx.x * chunk;
    int e1 = e0 + chunk; if (e1 > n_edges) e1 = n_edges;
    for (int e = e0 + (int)threadIdx.x; e < e1; e += 256) {
        int s = src[e], d = dst[e];
        int sb = s >> 7, db = d >> 7;
        int ps = atomicAdd(&cs[sb], 1);
        ss[((size_t)sb << CAPLOG) + ps] = (unsigned char)(s & 127);
        int pd = atomicAdd(&cd[db], 1);
        sd[((size_t)db << CAPLOG) + pd] = ((unsigned int)(d & 127) << 25) | (unsigned int)s;
    }
}

// One block per bucket b:
//  phase 1: count ss local ids -> norm_src.
//  phase 2: 256-bin count of sd keyed (local<<1 | src>=nhalf) -> scan ->
//           node_rng4 (start, mid, end) + sorted srt + norm_dst.
__global__ __launch_bounds__(256) void prep_a(
        const unsigned char* __restrict__ ss, const int* __restrict__ cnt_s,
        const unsigned int* __restrict__ sd, const int* __restrict__ cnt_d,
        float* __restrict__ norm_src, int4* __restrict__ node_rng4,
        unsigned short* __restrict__ srt, float* __restrict__ norm_dst,
        int n, int nhalf) {
    __shared__ int cnt[256], cur[256];
    __shared__ int wtot[4];
    const int b = blockIdx.x;
    const int tid = threadIdx.x;

    // ---- phase 1: src degree ----
    if (tid < 128) cnt[tid] = 0;
    __syncthreads();
    {
        int used = cnt_s[b];
        const unsigned char* p = ss + ((size_t)b << CAPLOG);
        for (int i = tid; i < used; i += 256) atomicAdd(&cnt[p[i]], 1);
    }
    __syncthreads();
    if (tid < 128) {
        int c = cnt[tid]; if (c < 1) c = 1;
        int node = (b << 7) + tid;
        if (node < n) norm_src[node] = 1.0f / sqrtf((float)c);
    }
    __syncthreads();

    // ---- phase 2: dst 256-bin counting sort ----
    cnt[tid] = 0;
    __syncthreads();
    int used = cnt_d[b];
    const unsigned int* p = sd + ((size_t)b << CAPLOG);
    for (int i = tid; i < used; i += 256) {
        unsigned int e = p[i];
        int key = ((int)(e >> 25) << 1) | ((int)(e & 0x1FFFFFFu) >= nhalf ? 1 : 0);
        atomicAdd(&cnt[key], 1);
    }
    __syncthreads();
    int lane = tid & 63, wid = tid >> 6;
    int v = cnt[tid];
    int incl = v;
    #pragma unroll
    for (int d = 1; d < 64; d <<= 1) {
        int t = __shfl_up(incl, d, 64);
        if (lane >= d) incl += t;
    }
    if (lane == 63) wtot[wid] = incl;
    __syncthreads();
    int pre = 0;
    #pragma unroll
    for (int k = 0; k < 3; ++k) if (k < wid) pre += wtot[k];
    cur[tid] = pre + incl - v;
    __syncthreads();
    if (tid < 128) {
        int start = cur[2 * tid];
        int mid   = cur[2 * tid + 1];
        int end   = mid + cnt[2 * tid + 1];
        int node = (b << 7) + tid;
        if (node < n) {
            int base = b << CAPLOG;
            node_rng4[node] = make_int4(base + start, base + mid, base + end, 0);
            int c = end - start; if (c < 1) c = 1;
            norm_dst[node] = 1.0f / sqrtf((float)c);
        }
    }
    __syncthreads();
    for (int i = tid; i < used; i += 256) {
        unsigned int e = p[i];
        int s = (int)(e & 0x1FFFFFFu);
        int key = ((int)(e >> 25) << 1) | (s >= nhalf ? 1 : 0);
        int pos = atomicAdd(&cur[key], 1);
        srt[((size_t)b << CAPLOG) + pos] = (unsigned short)(s & 0xFFFF);
    }
}

// Wide streaming cast: xb = bf16(h * norm_src). 16 threads per node row.
__global__ __launch_bounds__(256) void xcast(const float* __restrict__ h,
        const float* __restrict__ norm_src, unsigned short* __restrict__ xb,
        int n) {
    int idx = blockIdx.x * 256 + threadIdx.x;
    if (idx >= n * 16) return;
    int node = idx >> 4, c4 = (idx & 15) << 2;
    float s = norm_src[node];
    float4 v = *(const float4*)(h + (size_t)node * 64 + c4);
    ushort4 o;
    o.x = f2bf(v.x * s); o.y = f2bf(v.y * s);
    o.z = f2bf(v.z * s); o.w = f2bf(v.w * s);
    *(ushort4*)(xb + (size_t)node * 64 + c4) = o;
}

// Src-split gather, one wave per dst node, 24 edges in flight per round.
// phase 0: edges [start,mid)  (src < nhalf, table-half L2-resident),
//          nontemporal f32 partial store (no norm).
// phase 1: edges [mid,end), adds partial, *norm (+bias), final store
//          (bf16 row if write_bf, else f32+bias).
__global__ __launch_bounds__(256) void gather_ph(const unsigned short* __restrict__ xb,
        const unsigned short* __restrict__ srt, const int4* __restrict__ node_rng4,
        const float* __restrict__ nrm, const float* __restrict__ bias,
        float* __restrict__ accbuf, void* __restrict__ outp,
        int write_bf, int phase, int n_nodes) {
    int node = blockIdx.x * 4 + (threadIdx.x >> 6);
    if (node >= n_nodes) return;
    int lane = threadIdx.x & 63;
    int g  = lane >> 3;         // edge slot 0..7
    int c8 = (lane & 7) * 8;    // column base
    int4 rng = node_rng4[node];
    int a0 = phase ? rng.y : rng.x;
    int a1 = phase ? rng.z : rng.y;
    f32x4* ap = (f32x4*)(accbuf + (size_t)node * 64 + c8);
    float acc[8];
    #pragma unroll
    for (int j = 0; j < 8; ++j) acc[j] = 0.f;
    if (phase && g == 0) {
        f32x4 p0 = __builtin_nontemporal_load(ap);
        f32x4 p1 = __builtin_nontemporal_load(ap + 1);
        acc[0] = p0.x; acc[1] = p0.y; acc[2] = p0.z; acc[3] = p0.w;
        acc[4] = p1.x; acc[5] = p1.y; acc[6] = p1.z; acc[7] = p1.w;
    }
    for (int base = a0; base < a1; base += 24) {
        #pragma unroll
        for (int u = 0; u < 3; ++u) {
            int ei = base + u * 8 + g;
            int idx = ei < a1 ? ei : a1 - 1;
            float msk = ei < a1 ? 1.0f : 0.0f;
            int s = srt[idx];
            const uint4 v = *(const uint4*)(xb + (size_t)s * 64 + c8);
            acc[0] = fmaf(bf2f_lo(v.x), msk, acc[0]);
            acc[1] = fmaf(bf2f_hi(v.x), msk, acc[1]);
            acc[2] = fmaf(bf2f_lo(v.y), msk, acc[2]);
            acc[3] = fmaf(bf2f_hi(v.y), msk, acc[3]);
            acc[4] = fmaf(bf2f_lo(v.z), msk, acc[4]);
            acc[5] = fmaf(bf2f_hi(v.z), msk, acc[5]);
            acc[6] = fmaf(bf2f_lo(v.w), msk, acc[6]);
            acc[7] = fmaf(bf2f_hi(v.w), msk, acc[7]);
        }
    }
    #pragma unroll
    for (int off = 8; off < 64; off <<= 1) {
        #pragma unroll
        for (int j = 0; j < 8; ++j) acc[j] += __shfl_xor(acc[j], off, 64);
    }
    if (g == 0) {
        if (!phase) {
            f32x4 q0; q0.x = acc[0]; q0.y = acc[1]; q0.z = acc[2]; q0.w = acc[3];
            f32x4 q1; q1.x = acc[4]; q1.y = acc[5]; q1.z = acc[6]; q1.w = acc[7];
            __builtin_nontemporal_store(q0, ap);
            __builtin_nontemporal_store(q1, ap + 1);
        } else {
            float s = nrm[node];
            float r[8];
            #pragma unroll
            for (int j = 0; j < 8; ++j) r[j] = acc[j] * s;
            if (write_bf) {
                unsigned short rb[8];
                #pragma unroll
                for (int j = 0; j < 8; ++j) rb[j] = f2bf(r[j]);
                unsigned short* o = (unsigned short*)outp + (size_t)node * 64 + c8;
                *(ushort4*)(o)     = make_ushort4(rb[0], rb[1], rb[2], rb[3]);
                *(ushort4*)(o + 4) = make_ushort4(rb[4], rb[5], rb[6], rb[7]);
            } else {
                if (bias) {
                    #pragma unroll
                    for (int j = 0; j < 8; ++j) r[j] += bias[c8 + j];
                }
                float* o = (float*)outp + (size_t)node * 64 + c8;
                *(float4*)(o)     = make_float4(r[0], r[1], r[2], r[3]);
                *(float4*)(o + 4) = make_float4(r[4], r[5], r[6], r[7]);
            }
        }
    }
}

// MFMA fused both layers per 64-node tile. 4 waves, wave w owns nodes
// m0+w*16..+15.  Layouts (verified per guide m89/m91/m120):
//   A-frag  lane l: A[m = l&15][k = (l>>4)*8 + j]     (bf16x8, 16B/lane)
//   B-frag  lane l: B[k = (l>>4)*8 + j][n = l&15]
//   C/D     lane l reg r: D[m = (l>>4)*4 + r][n = l&15]
// W1t/W2t images pre-built in global; staging is pure uint4 LDS copy.
__global__ __launch_bounds__(256) void gemm12(const unsigned short* __restrict__ Ab,
        const unsigned short* __restrict__ w1t_g, const float* __restrict__ b1,
        const float* __restrict__ norm, const unsigned short* __restrict__ w2t_g,
        unsigned short* __restrict__ y2b, int n) {
    __shared__ __align__(16) unsigned short W1t[128 * 72];
    __shared__ __align__(16) unsigned short W2t[64 * 136];
    __shared__ __align__(16) unsigned short Hs[64 * 136];
    __shared__ float b1s[128];
    const int tid = threadIdx.x;

    {
        const uint4* s1 = (const uint4*)w1t_g;
        uint4* d1 = (uint4*)W1t;
        for (int i = tid; i < 1152; i += 256) d1[i] = s1[i];
        const uint4* s2 = (const uint4*)w2t_g;
        uint4* d2 = (uint4*)W2t;
        for (int i = tid; i < 1088; i += 256) d2[i] = s2[i];
    }
    if (tid < 128) b1s[tid] = b1[tid];
    __syncthreads();

    const int w  = tid >> 6;
    const int l  = tid & 63;
    const int ln = l & 15;
    const int q  = l >> 4;
    const int m0 = blockIdx.x * 64 + w * 16;

    int arow = m0 + ln; if (arow > n - 1) arow = n - 1;
    const unsigned short* arp = Ab + (size_t)arow * 64 + q * 8;
    bf16x8 a0 = *(const bf16x8*)(arp);
    bf16x8 a1 = *(const bf16x8*)(arp + 32);

    float ns[4];
    #pragma unroll
    for (int r = 0; r < 4; ++r) {
        int node = m0 + q * 4 + r;
        ns[r] = norm[node < n ? node : n - 1];
    }

    #pragma unroll
    for (int c = 0; c < 8; ++c) {
        const unsigned short* bp = W1t + (c * 16 + ln) * 72 + q * 8;
        bf16x8 b0 = *(const bf16x8*)(bp);
        bf16x8 bk = *(const bf16x8*)(bp + 32);
        f32x4 acc = {0.f, 0.f, 0.f, 0.f};
        acc = __builtin_amdgcn_mfma_f32_16x16x32_bf16(a0, b0, acc, 0, 0, 0);
        acc = __builtin_amdgcn_mfma_f32_16x16x32_bf16(a1, bk, acc, 0, 0, 0);
        int col = c * 16 + ln;
        float bb = b1s[col];
        #pragma unroll
        for (int r = 0; r < 4; ++r) {
            float v = acc[r] + bb;
            v = v > 0.f ? v : 0.f;
            Hs[(w * 16 + q * 4 + r) * 136 + col] = f2bf(v * ns[r]);
        }
    }
    __syncthreads();

    const unsigned short* hp = Hs + (size_t)(w * 16 + ln) * 136 + q * 8;
    bf16x8 h0 = *(const bf16x8*)(hp);
    bf16x8 h1 = *(const bf16x8*)(hp + 32);
    bf16x8 h2 = *(const bf16x8*)(hp + 64);
    bf16x8 h3 = *(const bf16x8*)(hp + 96);
    #pragma unroll
    for (int c = 0; c < 4; ++c) {
        const unsigned short* bp = W2t + (c * 16 + ln) * 136 + q * 8;
        f32x4 acc = {0.f, 0.f, 0.f, 0.f};
        acc = __builtin_amdgcn_mfma_f32_16x16x32_bf16(h0, *(const bf16x8*)(bp),      acc, 0, 0, 0);
        acc = __builtin_amdgcn_mfma_f32_16x16x32_bf16(h1, *(const bf16x8*)(bp + 32), acc, 0, 0, 0);
        acc = __builtin_amdgcn_mfma_f32_16x16x32_bf16(h2, *(const bf16x8*)(bp + 64), acc, 0, 0, 0);
        acc = __builtin_amdgcn_mfma_f32_16x16x32_bf16(h3, *(const bf16x8*)(bp + 96), acc, 0, 0, 0);
        #pragma unroll
        for (int r = 0; r < 4; ++r) {
            int node = m0 + q * 4 + r;
            if (node < n)
                y2b[(size_t)node * 64 + c * 16 + ln] = f2bf(acc[r]);
        }
    }
}

extern "C" void kernel_launch(void* const* d_in, const int* in_sizes, int n_in,
                              void* d_out, int out_size, void* d_ws, size_t ws_size,
                              hipStream_t stream) {
    const float* h   = (const float*)d_in[0];
    const int*   src = (const int*)d_in[1];
    const int*   dst = (const int*)d_in[2];
    const float* W1  = (const float*)d_in[3];
    const float* b1  = (const float*)d_in[4];
    const float* W2  = (const float*)d_in[5];
    const float* b2  = (const float*)d_in[6];
    float* out = (float*)d_out;

    const int n = in_sizes[0] / 64;
    const int E = in_sizes[1];
    const int nb = (n + 127) >> 7;
    const int nhalf = n >> 1;

    char* p = (char*)d_ws;
    auto alloc = [&](size_t bytes) {
        void* r = (void*)p;
        p += (bytes + 255) & ~(size_t)255;
        return r;
    };
    float* norm_src      = (float*)alloc((size_t)n * 4);
    float* norm_dst      = (float*)alloc((size_t)n * 4);
    int4* node_rng4      = (int4*)alloc((size_t)n * 16);
    int* cnt_s           = (int*)alloc((size_t)nb * 4);
    int* cnt_d           = (int*)alloc((size_t)nb * 4);
    int* hist            = (int*)alloc((size_t)2 * NBLK * NBMAX * 4);
    int* offs            = (int*)alloc((size_t)2 * NBLK * NBMAX * 4);
    unsigned int* sd     = (unsigned int*)alloc((size_t)nb * CAP * 4);
    float* accbuf        = (float*)alloc((size_t)n * 64 * 4);
    unsigned short* xb   = (unsigned short*)alloc((size_t)n * 64 * 2);
    unsigned short* agg1b= (unsigned short*)alloc((size_t)n * 64 * 2);
    unsigned short* y2b  = (unsigned short*)alloc((size_t)n * 64 * 2);
    unsigned short* srt  = (unsigned short*)alloc((size_t)nb * CAP * 2);
    unsigned char* ssb   = (unsigned char*)alloc((size_t)nb * CAP);
    unsigned short* w1t_g= (unsigned short*)alloc((size_t)128 * 72 * 2);
    unsigned short* w2t_g= (unsigned short*)alloc((size_t)64 * 136 * 2);

    hist_edges<<<NBLK + 1, 256, 0, stream>>>(src, dst, hist, E, nb,
                                             W1, W2, w1t_g, w2t_g);
    scan_hist<<<2 * nb, 256, 0, stream>>>(hist, offs, cnt_s, cnt_d, nb);
    scatter_binned<<<NBLK, 256, 0, stream>>>(src, dst, offs, ssb, sd, E, nb);
    prep_a<<<nb, 256, 0, stream>>>(ssb, cnt_s, sd, cnt_d, norm_src,
                                   node_rng4, srt, norm_dst, n, nhalf);
    xcast<<<(n * 16 + 255) / 256, 256, 0, stream>>>(h, norm_src, xb, n);

    int gb = (n + 3) / 4;
    // stage 1: agg over xb -> agg1b (bf16)
    gather_ph<<<gb, 256, 0, stream>>>(xb, srt, node_rng4, norm_dst, nullptr,
                                      accbuf, (void*)agg1b, 1, 0, n);
    gather_ph<<<gb, 256, 0, stream>>>(xb, srt, node_rng4, norm_dst, nullptr,
                                      accbuf, (void*)agg1b, 1, 1, n);

    int tb = (n + 63) / 64;
    gemm12<<<tb, 256, 0, stream>>>(agg1b, w1t_g, b1, norm_src, w2t_g, y2b, n);

    // stage 2: agg over y2b -> out (f32, +b2)
    gather_ph<<<gb, 256, 0, stream>>>(y2b, srt, node_rng4, norm_dst, b2,
                                      accbuf, (void*)out, 0, 0, n);
    gather_ph<<<gb, 256, 0, stream>>>(y2b, srt, node_rng4, norm_dst, b2,
                                      accbuf, (void*)out, 0, 1, n);
}